// Round 2
// baseline (757.464 us; speedup 1.0000x reference)
//
#include <hip/hip_runtime.h>

#define NN 256
#define NP1 257
#define STRIDE 264          // row stride in floats (264*4 B rows)
#define NEGV -1000000000.0f
#define MIN_LOOP 3
#define BLOCK 1024

// E[i][m] = best score of window starting at i, length m   (row-major, stride STRIDE)
// G[e][m] = E[e-m][m]  (indexed by window END e = i+m)     (row-major, stride STRIDE)
// bif(i,l) = max_{m=1..l-1} E[i][m] + E[i+m][l-m]
//          = max_{m=1..l-1} Erow_i[m] + Grow_{i+l}[l-m]    -> two contiguous rows.
__global__ __launch_bounds__(BLOCK) void nussinov_kernel(
    const float* __restrict__ sp,   // (B, N, N)
    const float* __restrict__ su,   // (B, N)
    float* __restrict__ out,        // (B)
    float* __restrict__ ws)
{
    const int b   = blockIdx.x;
    const int tid = threadIdx.x;

    float* E = ws + (size_t)b * (2u * NP1 * STRIDE);
    float* G = E + (size_t)NP1 * STRIDE;
    const float* spb = sp + (size_t)b * NN * NN;
    const float* sub = su + (size_t)b * NN;

    __shared__ float su_s[NP1];

    // ---- init: column 0 = 0 (never read, but defined), column 1 = su_pad ----
    if (tid <= NN) {
        float v = (tid < NN) ? sub[tid] : 0.0f;   // su_pad
        su_s[tid] = v;
        E[(size_t)tid * STRIDE + 0] = 0.0f;
        E[(size_t)tid * STRIDE + 1] = v;
        G[(size_t)tid * STRIDE + 0] = 0.0f;
        if (tid >= 1) G[(size_t)tid * STRIDE + 1] = sub[tid - 1]; // G[e][1] = su[e-1]
    }
    __syncthreads();

    // ---- wavefront over window length l ----
    for (int l = 2; l <= NN; ++l) {
        const int W = NN - l + 1;           // windows i = 0..W-1
        // threads-per-window T: pow2, <=64, no wider than the reduction, fill the block
        int T = 1;
        while (T < 64 && T < l - 1 && T * W < BLOCK) T <<= 1;
        const int NG   = BLOCK / T;
        const int g0   = tid / T;
        const int lane = tid % T;

        for (int i = g0; i < W; i += NG) {
            const float* __restrict__ Erow = E + (size_t)i * STRIDE;
            const float* __restrict__ Grow = G + (size_t)(i + l) * STRIDE;

            // max-plus reduction over m = 1..l-1, strided by T, 4 accumulators
            float b0 = NEGV, b1 = NEGV, b2 = NEGV, b3 = NEGV;
            int m = 1 + lane;
            const int mend = l - 1;
            for (; m + 3 * T <= mend; m += 4 * T) {
                b0 = fmaxf(b0, Erow[m]         + Grow[l - m]);
                b1 = fmaxf(b1, Erow[m +     T] + Grow[l - m -     T]);
                b2 = fmaxf(b2, Erow[m + 2 * T] + Grow[l - m - 2 * T]);
                b3 = fmaxf(b3, Erow[m + 3 * T] + Grow[l - m - 3 * T]);
            }
            for (; m <= mend; m += T) b0 = fmaxf(b0, Erow[m] + Grow[l - m]);
            float best = fmaxf(fmaxf(b0, b1), fmaxf(b2, b3));

            // subgroup reduce (T <= 64, groups are T-aligned contiguous lanes)
            for (int off = T >> 1; off > 0; off >>= 1)
                best = fmaxf(best, __shfl_xor(best, off, 64));

            if (lane == 0) {
                const int j = i + l - 1;
                const float c1_next = E[(size_t)(i + 1) * STRIDE + (l - 1)];
                const float unl = su_s[i] + c1_next;          // i unpaired
                const float unr = su_s[j] + Erow[l - 1];      // j unpaired
                float v = fmaxf(fmaxf(unl, unr), best);
                if (l - 1 > MIN_LOOP) {                       // i pairs j
                    const float pr = spb[(size_t)i * NN + j]
                                   + E[(size_t)(i + 1) * STRIDE + (l - 2)];
                    v = fmaxf(v, pr);
                }
                // step-l writes (column l) are disjoint from step-l reads (cols <= l-1)
                E[(size_t)i * STRIDE + l]       = v;
                G[(size_t)(i + l) * STRIDE + l] = v;
            }
        }
        __threadfence_block();
        __syncthreads();
    }

    if (tid == 0) out[b] = E[NN];   // E[0][N]
}

extern "C" void kernel_launch(void* const* d_in, const int* in_sizes, int n_in,
                              void* d_out, int out_size, void* d_ws, size_t ws_size,
                              hipStream_t stream) {
    const float* sp = (const float*)d_in[0];  // score_paired  (B,N,N) f32
    const float* su = (const float*)d_in[1];  // score_unpaired (B,N)  f32
    float* out = (float*)d_out;               // (B) f32
    float* ws  = (float*)d_ws;                // 2 * B * 257 * 264 floats ~ 2.1 MB
    const int B = in_sizes[1] / NN;
    nussinov_kernel<<<B, BLOCK, 0, stream>>>(sp, su, out, ws);
}